// Round 4
// baseline (304.566 us; speedup 1.0000x reference)
//
#include <hip/hip_runtime.h>
#include <cstdint>
#include <cstddef>

#define SEQ 4096
#define DH 2048
#define DOUT 1024

typedef float f32x4 __attribute__((ext_vector_type(4)));
typedef __bf16 bf16x8 __attribute__((ext_vector_type(8)));

// ---- helpers --------------------------------------------------------------

__device__ __forceinline__ unsigned short f2bf(float f) {
  // round-to-nearest-even fp32 -> bf16 (inputs are finite; no NaN handling)
  unsigned int u = __float_as_uint(f);
  unsigned int r = (u + 0x7FFFu + ((u >> 16) & 1u)) >> 16;
  return (unsigned short)r;
}

__device__ __forceinline__ void g2l16(const unsigned short* g, unsigned short* l) {
  // async global -> LDS, 16 bytes per lane. LDS side is wave-uniform base + lane*16.
  __builtin_amdgcn_global_load_lds((__attribute__((address_space(1))) void*)(void*)g,
                                   (__attribute__((address_space(3))) void*)l, 16, 0, 0);
}

// ---- kernel 1: per-row mean / rstd of gate half ---------------------------

__global__ __launch_bounds__(256) void ln_stats(const float* __restrict__ x,
                                                float* __restrict__ mv,
                                                float* __restrict__ rv) {
  int row = blockIdx.x;
  const float4* g4 = (const float4*)(x + (size_t)row * (2 * DH) + DH);
  float4 a = g4[threadIdx.x];
  float4 b = g4[threadIdx.x + 256];
  float s  = a.x + a.y + a.z + a.w + b.x + b.y + b.z + b.w;
  float s2 = a.x * a.x + a.y * a.y + a.z * a.z + a.w * a.w +
             b.x * b.x + b.y * b.y + b.z * b.z + b.w * b.w;
#pragma unroll
  for (int o = 32; o > 0; o >>= 1) {
    s  += __shfl_down(s, o);
    s2 += __shfl_down(s2, o);
  }
  __shared__ float red[8];
  int wave = threadIdx.x >> 6;
  if ((threadIdx.x & 63) == 0) { red[wave] = s; red[wave + 4] = s2; }
  __syncthreads();
  if (threadIdx.x == 0) {
    float S  = red[0] + red[1] + red[2] + red[3];
    float S2 = red[4] + red[5] + red[6] + red[7];
    float mean = S * (1.0f / DH);
    float var  = S2 * (1.0f / DH) - mean * mean;  // ddof=0, matches jnp.var
    mv[row] = mean;
    rv[row] = rsqrtf(var + 1e-5f);
  }
}

// ---- kernel 2: normalize + scale + transpose + cast -> gateT[d][n] bf16 ---

__global__ __launch_bounds__(256) void norm_tr(const float* __restrict__ x,
                                               const float* __restrict__ mv,
                                               const float* __restrict__ rv,
                                               const float* __restrict__ lns,
                                               unsigned short* __restrict__ gateT) {
  __shared__ float tile[64][65];  // +1 pad: conflict-free transposed reads
  int d0 = blockIdx.x * 64;  // d-tile (0..2047)
  int n0 = blockIdx.y * 64;  // n-tile (0..4095)
#pragma unroll
  for (int i = 0; i < 16; i++) {
    int idx = threadIdx.x + i * 256;
    int r = idx >> 6, c = idx & 63;  // r = n offset, c = d offset (coalesced in c)
    float v = x[(size_t)(n0 + r) * (2 * DH) + DH + d0 + c];
    tile[r][c] = (v - mv[n0 + r]) * rv[n0 + r];
  }
  __syncthreads();
#pragma unroll
  for (int i = 0; i < 16; i++) {
    int idx = threadIdx.x + i * 256;
    int dr = idx >> 6, nc = idx & 63;  // coalesced in nc
    float v = tile[nc][dr] * lns[d0 + dr];
    gateT[(size_t)(d0 + dr) * SEQ + n0 + nc] = f2bf(v);
  }
}

// ---- kernel 3: tril-masked cast w fp32 -> bf16 ----------------------------

__global__ __launch_bounds__(256) void cast_w_tril(const float* __restrict__ w,
                                                   unsigned short* __restrict__ wb) {
  size_t e = ((size_t)blockIdx.x * 256 + threadIdx.x) * 8;
  int m = (int)(e >> 12);    // row (4096 = 2^12 cols)
  int k = (int)(e & 4095);   // col
  uint4 o;
  if (k + 7 <= m) {  // fully inside lower triangle
    const float4* s = (const float4*)(w + e);
    float4 a = s[0], b = s[1];
    o.x = (unsigned)f2bf(a.x) | ((unsigned)f2bf(a.y) << 16);
    o.y = (unsigned)f2bf(a.z) | ((unsigned)f2bf(a.w) << 16);
    o.z = (unsigned)f2bf(b.x) | ((unsigned)f2bf(b.y) << 16);
    o.w = (unsigned)f2bf(b.z) | ((unsigned)f2bf(b.w) << 16);
  } else if (k > m) {  // fully above diagonal: no read needed
    o.x = o.y = o.z = o.w = 0u;
  } else {  // straddles the diagonal
    unsigned short t[8];
#pragma unroll
    for (int j = 0; j < 8; j++) t[j] = (k + j <= m) ? f2bf(w[e + j]) : (unsigned short)0;
    o.x = (unsigned)t[0] | ((unsigned)t[1] << 16);
    o.y = (unsigned)t[2] | ((unsigned)t[3] << 16);
    o.z = (unsigned)t[4] | ((unsigned)t[5] << 16);
    o.w = (unsigned)t[6] | ((unsigned)t[7] << 16);
  }
  *(uint4*)(wb + e) = o;
}

// ---- kernel 4: transpose + cast proj_w -> projT[j][d] bf16 ----------------

__global__ __launch_bounds__(256) void proj_tr(const float* __restrict__ pw,
                                               unsigned short* __restrict__ pT) {
  __shared__ float tile[64][65];
  int j0 = blockIdx.x * 64;  // out-col tile (0..1023)
  int d0 = blockIdx.y * 64;  // d tile (0..2047)
#pragma unroll
  for (int i = 0; i < 16; i++) {
    int idx = threadIdx.x + i * 256;
    int r = idx >> 6, c = idx & 63;  // r = d offset, c = j offset
    tile[r][c] = pw[(size_t)(d0 + r) * DOUT + j0 + c];
  }
  __syncthreads();
#pragma unroll
  for (int i = 0; i < 16; i++) {
    int idx = threadIdx.x + i * 256;
    int jr = idx >> 6, dc = idx & 63;
    pT[(size_t)(j0 + jr) * DH + d0 + dc] = f2bf(tile[dc][jr]);
  }
}

// ---- MFMA GEMM, 128x128 tile, BK=64, single-barrier double-buffered -------
// C = A(MxK) * BT(NxK)^T, bf16 in / fp32 acc. 4 waves in 2x2 grid, each wave
// owns a 64x64 subtile (4x4 16x16 acc tiles): LDS intensity 32 FLOP/byte,
// 32 MFMA + 16 ds_read_b128 per wave per BK=64 iter -> MFMA-balanced.
//
// Pipeline: stage(i+1) -> buf[(i+1)&1] (async global_load_lds), compute(i) on
// buf[i&1], ONE __syncthreads() (its compiler vmcnt(0)+lgkmcnt(0) drain lands
// after ~600 cyc of compute has covered the load latency). Grid is 1 block/CU
// by design: the pipeline, not TLP, hides staging.
//
// PAIR (GEMM1 causal): block p processes row-blocks {p, 31-p} back-to-back as
// one flat 66-iteration pipeline (2(p+1) + 2(32-p) = 66 for every p) -> fully
// uniform 256-block grid. A is pre-masked tril so diagonal tiles are correct.
// Tile-1 epilogue fires right after its last compute, pre-barrier, so its
// stores overlap the already-in-flight staging of tile 2.
// EPI==1: P[m][n] = bf16( xfull[m][n] * (acc + rbias[m]) )
// EPI==2: out[m][n] = acc + cbias[n]
//
// LDS: 128 B rows (BK=64) = exactly 32 banks, XOR-8 chunk swizzle
// (phys chunk = data chunk ^ (row&7)) -> 0 bank conflicts (verified R3).

template <bool PAIR, int EPI>
__global__ __launch_bounds__(256, 1) void gemm128(const unsigned short* __restrict__ A,
                                                  const unsigned short* __restrict__ BT,
                                                  const float* __restrict__ xfull,
                                                  const float* __restrict__ rbias,
                                                  unsigned short* __restrict__ Pout,
                                                  const float* __restrict__ cbias,
                                                  float* __restrict__ out,
                                                  int N, int K) {
  constexpr int BK = 64;
  __shared__ unsigned short sA[2][128 * BK];
  __shared__ unsigned short sB[2][128 * BK];

  const int tid = threadIdx.x;
  const int lane = tid & 63, wave = tid >> 6;
  const int quad = lane >> 4, l16 = lane & 15;
  const int wm = wave >> 1, wn = wave & 1;
  const int bn0 = blockIdx.x * 128;
  const int p = blockIdx.y;

  const int bm0a = p * 128;
  const int bm0b = PAIR ? (2 * (int)gridDim.y - 1 - p) * 128 : 0;
  const int e1 = PAIR ? 2 * (p + 1) : (K / BK);
  const int total = PAIR ? (2 + 4 * (int)gridDim.y) : (K / BK);

  // per-thread staging offsets (shared by A and B: BM == BN == 128)
  // slot s (0..1023): row = s>>3, phys chunk = s&7, data chunk = (s&7)^(row&7)
  int sOff[4], sDst[4];
#pragma unroll
  for (int r = 0; r < 4; r++) {
    int idx = r * 256 + tid;
    int row = idx >> 3;
    sOff[r] = row * K + (((idx & 7) ^ (row & 7)) * 8);
    sDst[r] = idx * 8;
  }

  f32x4 acc[4][4] = {};

  // ---- stage(i) into buf b ----
  auto stage = [&](int i, int b) {
    int kk, bm;
    if (!PAIR || i < e1) { kk = i * BK; bm = bm0a; }
    else                 { kk = (i - e1) * BK; bm = bm0b; }
    const unsigned short* Ab = A + (size_t)bm * K + kk;
    const unsigned short* Bb = BT + (size_t)bn0 * K + kk;
#pragma unroll
    for (int r = 0; r < 4; r++) g2l16(Ab + sOff[r], &sA[b][sDst[r]]);
#pragma unroll
    for (int r = 0; r < 4; r++) g2l16(Bb + sOff[r], &sB[b][sDst[r]]);
  };

  // ---- compute on buf b ----
  auto compute = [&](int b) {
    bf16x8 af[2][4], bf[2][4];
#pragma unroll
    for (int h = 0; h < 2; h++) {
#pragma unroll
      for (int i = 0; i < 4; i++) {
        int R = wm * 64 + i * 16 + l16;
        af[h][i] = *(const bf16x8*)&sA[b][R * BK + (((h * 4 + quad) ^ (R & 7)) * 8)];
      }
#pragma unroll
      for (int j = 0; j < 4; j++) {
        int R = wn * 64 + j * 16 + l16;
        bf[h][j] = *(const bf16x8*)&sB[b][R * BK + (((h * 4 + quad) ^ (R & 7)) * 8)];
      }
    }
#pragma unroll
    for (int h = 0; h < 2; h++)
#pragma unroll
      for (int i = 0; i < 4; i++)
#pragma unroll
        for (int j = 0; j < 4; j++)
          acc[i][j] = __builtin_amdgcn_mfma_f32_16x16x32_bf16(af[h][i], bf[h][j], acc[i][j], 0, 0, 0);
  };

  // ---- epilogue: C/D layout col = lane&15, row = quad*4 + reg -------------
  auto epilogue = [&](int bm0) {
#pragma unroll
    for (int i = 0; i < 4; i++) {
#pragma unroll
      for (int j = 0; j < 4; j++) {
        int col = bn0 + wn * 64 + j * 16 + l16;
#pragma unroll
        for (int r = 0; r < 4; r++) {
          int row = bm0 + wm * 64 + i * 16 + quad * 4 + r;
          float v = acc[i][j][r];
          if (EPI == 1) {
            float g = v + rbias[row];
            float pv = xfull[(size_t)row * (2 * DH) + col] * g;
            Pout[(size_t)row * N + col] = f2bf(pv);
          } else {
            out[(size_t)row * N + col] = v + cbias[col];
          }
        }
      }
    }
  };

  stage(0, 0);
  __syncthreads();
  for (int i = 0; i < total; i++) {
    if (i + 1 < total) stage(i + 1, (i + 1) & 1);
    compute(i & 1);
    if (PAIR && i == e1 - 1) {
      epilogue(bm0a);
#pragma unroll
      for (int a = 0; a < 4; a++)
#pragma unroll
        for (int bj = 0; bj < 4; bj++) acc[a][bj] = (f32x4){0.f, 0.f, 0.f, 0.f};
    }
    __syncthreads();
  }
  epilogue(PAIR ? bm0b : bm0a);
}

// ---- launch ---------------------------------------------------------------

extern "C" void kernel_launch(void* const* d_in, const int* in_sizes, int n_in,
                              void* d_out, int out_size, void* d_ws, size_t ws_size,
                              hipStream_t stream) {
  (void)in_sizes; (void)n_in; (void)out_size; (void)ws_size;
  const float* x   = (const float*)d_in[0];
  const float* lns = (const float*)d_in[1];
  const float* w   = (const float*)d_in[2];
  const float* sb  = (const float*)d_in[3];
  const float* pw  = (const float*)d_in[4];
  const float* pb  = (const float*)d_in[5];
  float* out = (float*)d_out;

  char* p = (char*)d_ws;
  unsigned short* gateT = (unsigned short*)p; p += (size_t)DH * SEQ * 2;    // 16 MB
  unsigned short* wb    = (unsigned short*)p; p += (size_t)SEQ * SEQ * 2;   // 32 MB
  unsigned short* projT = (unsigned short*)p; p += (size_t)DOUT * DH * 2;   //  4 MB
  unsigned short* Pbuf  = (unsigned short*)p; p += (size_t)SEQ * DH * 2;    // 16 MB
  float* mv = (float*)p; p += (size_t)SEQ * 4;
  float* rv = (float*)p; p += (size_t)SEQ * 4;

  ln_stats<<<SEQ, 256, 0, stream>>>(x, mv, rv);
  norm_tr<<<dim3(DH / 64, SEQ / 64), 256, 0, stream>>>(x, mv, rv, lns, gateT);
  cast_w_tril<<<(int)(((size_t)SEQ * SEQ / 8) / 256), 256, 0, stream>>>(w, wb);
  proj_tr<<<dim3(DOUT / 64, DH / 64), 256, 0, stream>>>(pw, projT);

  // GEMM1: gate2 = tril(w) @ gate  (M=4096, N=2048, K=4096)
  // Triangular pairing at 128-tile: block p does {p, 31-p} -> 66 iters each,
  // grid (16,16)=256 uniform blocks, double-buffered pipeline.
  gemm128<true, 1><<<dim3(DH / 128, SEQ / 256), 256, 0, stream>>>(
      wb, gateT, x, sb, Pbuf, nullptr, nullptr, DH, SEQ);
  // GEMM2: out = P @ proj_w + proj_b  (M=4096, N=1024, K=2048)
  // grid (8,32)=256 uniform blocks, 32 iters.
  gemm128<false, 2><<<dim3(DOUT / 128, SEQ / 128), 256, 0, stream>>>(
      Pbuf, projT, nullptr, nullptr, nullptr, pb, out, DOUT, DH);
}

// Round 5
// 270.172 us; speedup vs baseline: 1.1273x; 1.1273x over previous
//
#include <hip/hip_runtime.h>
#include <cstdint>
#include <cstddef>

#define SEQ 4096
#define DH 2048
#define DOUT 1024

typedef float f32x4 __attribute__((ext_vector_type(4)));
typedef __bf16 bf16x8 __attribute__((ext_vector_type(8)));

// ---- helpers --------------------------------------------------------------

__device__ __forceinline__ unsigned short f2bf(float f) {
  // round-to-nearest-even fp32 -> bf16 (inputs are finite; no NaN handling)
  unsigned int u = __float_as_uint(f);
  unsigned int r = (u + 0x7FFFu + ((u >> 16) & 1u)) >> 16;
  return (unsigned short)r;
}

__device__ __forceinline__ void g2l16(const unsigned short* g, unsigned short* l) {
  // async global -> LDS, 16 bytes per lane. LDS side is wave-uniform base + lane*16.
  __builtin_amdgcn_global_load_lds((__attribute__((address_space(1))) void*)(void*)g,
                                   (__attribute__((address_space(3))) void*)l, 16, 0, 0);
}

// ---- kernel 1: per-row mean / rstd of gate half ---------------------------

__global__ __launch_bounds__(256) void ln_stats(const float* __restrict__ x,
                                                float* __restrict__ mv,
                                                float* __restrict__ rv) {
  int row = blockIdx.x;
  const float4* g4 = (const float4*)(x + (size_t)row * (2 * DH) + DH);
  float4 a = g4[threadIdx.x];
  float4 b = g4[threadIdx.x + 256];
  float s  = a.x + a.y + a.z + a.w + b.x + b.y + b.z + b.w;
  float s2 = a.x * a.x + a.y * a.y + a.z * a.z + a.w * a.w +
             b.x * b.x + b.y * b.y + b.z * b.z + b.w * b.w;
#pragma unroll
  for (int o = 32; o > 0; o >>= 1) {
    s  += __shfl_down(s, o);
    s2 += __shfl_down(s2, o);
  }
  __shared__ float red[8];
  int wave = threadIdx.x >> 6;
  if ((threadIdx.x & 63) == 0) { red[wave] = s; red[wave + 4] = s2; }
  __syncthreads();
  if (threadIdx.x == 0) {
    float S  = red[0] + red[1] + red[2] + red[3];
    float S2 = red[4] + red[5] + red[6] + red[7];
    float mean = S * (1.0f / DH);
    float var  = S2 * (1.0f / DH) - mean * mean;  // ddof=0, matches jnp.var
    mv[row] = mean;
    rv[row] = rsqrtf(var + 1e-5f);
  }
}

// ---- kernel 2: normalize + scale + transpose + cast -> gateT[d][n] bf16 ---

__global__ __launch_bounds__(256) void norm_tr(const float* __restrict__ x,
                                               const float* __restrict__ mv,
                                               const float* __restrict__ rv,
                                               const float* __restrict__ lns,
                                               unsigned short* __restrict__ gateT) {
  __shared__ float tile[64][65];  // +1 pad: conflict-free transposed reads
  int d0 = blockIdx.x * 64;  // d-tile (0..2047)
  int n0 = blockIdx.y * 64;  // n-tile (0..4095)
#pragma unroll
  for (int i = 0; i < 16; i++) {
    int idx = threadIdx.x + i * 256;
    int r = idx >> 6, c = idx & 63;  // r = n offset, c = d offset (coalesced in c)
    float v = x[(size_t)(n0 + r) * (2 * DH) + DH + d0 + c];
    tile[r][c] = (v - mv[n0 + r]) * rv[n0 + r];
  }
  __syncthreads();
#pragma unroll
  for (int i = 0; i < 16; i++) {
    int idx = threadIdx.x + i * 256;
    int dr = idx >> 6, nc = idx & 63;  // coalesced in nc
    float v = tile[nc][dr] * lns[d0 + dr];
    gateT[(size_t)(d0 + dr) * SEQ + n0 + nc] = f2bf(v);
  }
}

// ---- kernel 3: tril-masked cast w fp32 -> bf16 ----------------------------

__global__ __launch_bounds__(256) void cast_w_tril(const float* __restrict__ w,
                                                   unsigned short* __restrict__ wb) {
  size_t e = ((size_t)blockIdx.x * 256 + threadIdx.x) * 8;
  int m = (int)(e >> 12);    // row (4096 = 2^12 cols)
  int k = (int)(e & 4095);   // col
  uint4 o;
  if (k + 7 <= m) {  // fully inside lower triangle
    const float4* s = (const float4*)(w + e);
    float4 a = s[0], b = s[1];
    o.x = (unsigned)f2bf(a.x) | ((unsigned)f2bf(a.y) << 16);
    o.y = (unsigned)f2bf(a.z) | ((unsigned)f2bf(a.w) << 16);
    o.z = (unsigned)f2bf(b.x) | ((unsigned)f2bf(b.y) << 16);
    o.w = (unsigned)f2bf(b.z) | ((unsigned)f2bf(b.w) << 16);
  } else if (k > m) {  // fully above diagonal: no read needed
    o.x = o.y = o.z = o.w = 0u;
  } else {  // straddles the diagonal
    unsigned short t[8];
#pragma unroll
    for (int j = 0; j < 8; j++) t[j] = (k + j <= m) ? f2bf(w[e + j]) : (unsigned short)0;
    o.x = (unsigned)t[0] | ((unsigned)t[1] << 16);
    o.y = (unsigned)t[2] | ((unsigned)t[3] << 16);
    o.z = (unsigned)t[4] | ((unsigned)t[5] << 16);
    o.w = (unsigned)t[6] | ((unsigned)t[7] << 16);
  }
  *(uint4*)(wb + e) = o;
}

// ---- kernel 4: transpose + cast proj_w -> projT[j][d] bf16 ----------------

__global__ __launch_bounds__(256) void proj_tr(const float* __restrict__ pw,
                                               unsigned short* __restrict__ pT) {
  __shared__ float tile[64][65];
  int j0 = blockIdx.x * 64;  // out-col tile (0..1023)
  int d0 = blockIdx.y * 64;  // d tile (0..2047)
#pragma unroll
  for (int i = 0; i < 16; i++) {
    int idx = threadIdx.x + i * 256;
    int r = idx >> 6, c = idx & 63;  // r = d offset, c = j offset
    tile[r][c] = pw[(size_t)(d0 + r) * DOUT + j0 + c];
  }
  __syncthreads();
#pragma unroll
  for (int i = 0; i < 16; i++) {
    int idx = threadIdx.x + i * 256;
    int jr = idx >> 6, dc = idx & 63;
    pT[(size_t)(j0 + jr) * DH + d0 + dc] = f2bf(tile[dc][jr]);
  }
}

// ---- MFMA GEMM, 128x64 tile, BK=64, 2-barrier single-buffer ---------------
// C = A(MxK) * BT(NxK)^T, bf16 in / fp32 acc. 4 waves in a 2x2 grid; each
// wave owns a 64x32 subtile (4x2 16x16 acc tiles), 16 MFMA + 12 ds_read_b128
// per wave per BK=64 iter. LDS 24 KB single-buffered; grid 512 blocks = 2
// blocks/CU co-resident from t=0 (TLP hides the stage->barrier drain; R4
// proved source-level pipelining is compiler-defeated, so TLP is the only
// overlap mechanism).
//
// PAIR (GEMM1 causal): block (c,p) processes row-blocks {p, 31-p} back to
// back, each to its diagonal -> exactly 66 iters for every block (uniform,
// no tail). A is pre-masked tril so diagonal tiles are correct.
// EPI==1: P[m][n] = bf16( xfull[m][n] * (acc + rbias[m]) )
// EPI==2: out[m][n] = acc + cbias[n]
//
// LDS: 128 B rows (BK=64) = exactly 32 banks; XOR-8 chunk swizzle (phys
// chunk = data chunk ^ (row&7)) -> 0 bank conflicts (verified R3).

template <bool PAIR, int EPI>
__global__ __launch_bounds__(256) void gemm12864(const unsigned short* __restrict__ A,
                                                 const unsigned short* __restrict__ BT,
                                                 const float* __restrict__ xfull,
                                                 const float* __restrict__ rbias,
                                                 unsigned short* __restrict__ Pout,
                                                 const float* __restrict__ cbias,
                                                 float* __restrict__ out,
                                                 int N, int K) {
  constexpr int BK = 64;
  __shared__ unsigned short sA[128 * BK];  // 16 KB
  __shared__ unsigned short sB[64 * BK];   //  8 KB

  const int tid = threadIdx.x;
  const int lane = tid & 63, wave = tid >> 6;
  const int quad = lane >> 4, l16 = lane & 15;
  const int wm = wave >> 1, wn = wave & 1;
  const int bn0 = blockIdx.x * 64;
  const int p = blockIdx.y;

  // staging slot s: row = s>>3, phys chunk = s&7, data chunk = (s&7)^(row&7)
  int sOff[4], sDst[4];
#pragma unroll
  for (int r = 0; r < 4; r++) {
    int idx = r * 256 + tid;
    int row = idx >> 3;
    sOff[r] = row * K + (((idx & 7) ^ (row & 7)) * 8);
    sDst[r] = idx * 8;
  }

  const int nTiles = PAIR ? 2 : 1;
  for (int t = 0; t < nTiles; t++) {
    const int by = PAIR ? (t == 0 ? p : (2 * (int)gridDim.y - 1 - p)) : p;
    const int bm0 = by * 128;
    const int kEnd = PAIR ? (bm0 + 128) : K;

    const unsigned short* Ab = A + (size_t)bm0 * K;
    const unsigned short* Bb = BT + (size_t)bn0 * K;

    f32x4 acc[4][2] = {};

    for (int k0 = 0; k0 < kEnd; k0 += BK) {
#pragma unroll
      for (int r = 0; r < 4; r++) g2l16(Ab + k0 + sOff[r], &sA[sDst[r]]);
#pragma unroll
      for (int r = 0; r < 2; r++) g2l16(Bb + k0 + sOff[r], &sB[sDst[r]]);
      __syncthreads();  // drains vmcnt (global_load_lds) + barrier

      bf16x8 af[2][4], bf[2][2];
#pragma unroll
      for (int h = 0; h < 2; h++) {
#pragma unroll
        for (int i = 0; i < 4; i++) {
          int R = wm * 64 + i * 16 + l16;
          af[h][i] = *(const bf16x8*)&sA[R * BK + (((h * 4 + quad) ^ (R & 7)) * 8)];
        }
#pragma unroll
        for (int j = 0; j < 2; j++) {
          int R = wn * 32 + j * 16 + l16;
          bf[h][j] = *(const bf16x8*)&sB[R * BK + (((h * 4 + quad) ^ (R & 7)) * 8)];
        }
      }
#pragma unroll
      for (int h = 0; h < 2; h++)
#pragma unroll
        for (int i = 0; i < 4; i++)
#pragma unroll
          for (int j = 0; j < 2; j++)
            acc[i][j] = __builtin_amdgcn_mfma_f32_16x16x32_bf16(af[h][i], bf[h][j], acc[i][j], 0, 0, 0);
      __syncthreads();
    }

    // epilogue — C/D layout: col = lane&15, row = quad*4 + reg (m89-verified)
#pragma unroll
    for (int i = 0; i < 4; i++) {
#pragma unroll
      for (int j = 0; j < 2; j++) {
        int col = bn0 + wn * 32 + j * 16 + l16;
#pragma unroll
        for (int r = 0; r < 4; r++) {
          int row = bm0 + wm * 64 + i * 16 + quad * 4 + r;
          float v = acc[i][j][r];
          if (EPI == 1) {
            float g = v + rbias[row];
            float pv = xfull[(size_t)row * (2 * DH) + col] * g;
            Pout[(size_t)row * N + col] = f2bf(pv);
          } else {
            out[(size_t)row * N + col] = v + cbias[col];
          }
        }
      }
    }
    // next tile's staging is separated from this tile's LDS reads by the
    // second in-loop __syncthreads() above; epilogue touches only global.
  }
}

// ---- launch ---------------------------------------------------------------

extern "C" void kernel_launch(void* const* d_in, const int* in_sizes, int n_in,
                              void* d_out, int out_size, void* d_ws, size_t ws_size,
                              hipStream_t stream) {
  (void)in_sizes; (void)n_in; (void)out_size; (void)ws_size;
  const float* x   = (const float*)d_in[0];
  const float* lns = (const float*)d_in[1];
  const float* w   = (const float*)d_in[2];
  const float* sb  = (const float*)d_in[3];
  const float* pw  = (const float*)d_in[4];
  const float* pb  = (const float*)d_in[5];
  float* out = (float*)d_out;

  char* p = (char*)d_ws;
  unsigned short* gateT = (unsigned short*)p; p += (size_t)DH * SEQ * 2;    // 16 MB
  unsigned short* wb    = (unsigned short*)p; p += (size_t)SEQ * SEQ * 2;   // 32 MB
  unsigned short* projT = (unsigned short*)p; p += (size_t)DOUT * DH * 2;   //  4 MB
  unsigned short* Pbuf  = (unsigned short*)p; p += (size_t)SEQ * DH * 2;    // 16 MB
  float* mv = (float*)p; p += (size_t)SEQ * 4;
  float* rv = (float*)p; p += (size_t)SEQ * 4;

  ln_stats<<<SEQ, 256, 0, stream>>>(x, mv, rv);
  norm_tr<<<dim3(DH / 64, SEQ / 64), 256, 0, stream>>>(x, mv, rv, lns, gateT);
  cast_w_tril<<<(int)(((size_t)SEQ * SEQ / 8) / 256), 256, 0, stream>>>(w, wb);
  proj_tr<<<dim3(DOUT / 64, DH / 64), 256, 0, stream>>>(pw, projT);

  // GEMM1: gate2 = tril(w) @ gate  (M=4096, N=2048, K=4096)
  // 128x64 tiles, pairing {p, 31-p}: grid (32 cols, 16 pairs) = 512 uniform
  // 66-iter blocks = 2 blocks/CU, all co-resident.
  gemm12864<true, 1><<<dim3(DH / 64, SEQ / 256), 256, 0, stream>>>(
      wb, gateT, x, sb, Pbuf, nullptr, nullptr, DH, SEQ);
  // GEMM2: out = P @ proj_w + proj_b  (M=4096, N=1024, K=2048)
  // grid (16 cols, 32 rows) = 512 uniform 32-iter blocks = 2 blocks/CU.
  gemm12864<false, 2><<<dim3(DOUT / 64, SEQ / 128), 256, 0, stream>>>(
      Pbuf, projT, nullptr, nullptr, nullptr, pb, out, DOUT, DH);
}

// Round 6
// 262.933 us; speedup vs baseline: 1.1583x; 1.0275x over previous
//
#include <hip/hip_runtime.h>
#include <cstdint>
#include <cstddef>
#include <math.h>

#define SEQ 4096
#define DH 2048
#define DOUT 1024

typedef float f32x4 __attribute__((ext_vector_type(4)));
typedef __bf16 bf16x8 __attribute__((ext_vector_type(8)));

// ---- helpers --------------------------------------------------------------

__device__ __forceinline__ unsigned short f2bf(float f) {
  // round-to-nearest-even fp32 -> bf16 (inputs are finite; no NaN handling)
  unsigned int u = __float_as_uint(f);
  unsigned int r = (u + 0x7FFFu + ((u >> 16) & 1u)) >> 16;
  return (unsigned short)r;
}

__device__ __forceinline__ void g2l16(const unsigned short* g, unsigned short* l) {
  // async global -> LDS, 16 bytes per lane. LDS side is wave-uniform base + lane*16.
  __builtin_amdgcn_global_load_lds((__attribute__((address_space(1))) void*)(void*)g,
                                   (__attribute__((address_space(3))) void*)l, 16, 0, 0);
}

// ---- kernel 1: per-row mean / rstd of gate half ---------------------------

__global__ __launch_bounds__(256) void ln_stats(const float* __restrict__ x,
                                                float* __restrict__ mv,
                                                float* __restrict__ rv) {
  int row = blockIdx.x;
  const float4* g4 = (const float4*)(x + (size_t)row * (2 * DH) + DH);
  float4 a = g4[threadIdx.x];
  float4 b = g4[threadIdx.x + 256];
  float s  = a.x + a.y + a.z + a.w + b.x + b.y + b.z + b.w;
  float s2 = a.x * a.x + a.y * a.y + a.z * a.z + a.w * a.w +
             b.x * b.x + b.y * b.y + b.z * b.z + b.w * b.w;
#pragma unroll
  for (int o = 32; o > 0; o >>= 1) {
    s  += __shfl_down(s, o);
    s2 += __shfl_down(s2, o);
  }
  __shared__ float red[8];
  int wave = threadIdx.x >> 6;
  if ((threadIdx.x & 63) == 0) { red[wave] = s; red[wave + 4] = s2; }
  __syncthreads();
  if (threadIdx.x == 0) {
    float S  = red[0] + red[1] + red[2] + red[3];
    float S2 = red[4] + red[5] + red[6] + red[7];
    float mean = S * (1.0f / DH);
    float var  = S2 * (1.0f / DH) - mean * mean;  // ddof=0, matches jnp.var
    mv[row] = mean;
    rv[row] = rsqrtf(var + 1e-5f);
  }
}

// ---- kernel 2: normalize + scale + transpose + cast -> gateT[d][n] bf16 ---

__global__ __launch_bounds__(256) void norm_tr(const float* __restrict__ x,
                                               const float* __restrict__ mv,
                                               const float* __restrict__ rv,
                                               const float* __restrict__ lns,
                                               unsigned short* __restrict__ gateT) {
  __shared__ float tile[64][65];  // +1 pad: conflict-free transposed reads
  int d0 = blockIdx.x * 64;  // d-tile (0..2047)
  int n0 = blockIdx.y * 64;  // n-tile (0..4095)
#pragma unroll
  for (int i = 0; i < 16; i++) {
    int idx = threadIdx.x + i * 256;
    int r = idx >> 6, c = idx & 63;  // r = n offset, c = d offset (coalesced in c)
    float v = x[(size_t)(n0 + r) * (2 * DH) + DH + d0 + c];
    tile[r][c] = (v - mv[n0 + r]) * rv[n0 + r];
  }
  __syncthreads();
#pragma unroll
  for (int i = 0; i < 16; i++) {
    int idx = threadIdx.x + i * 256;
    int dr = idx >> 6, nc = idx & 63;  // coalesced in nc
    float v = tile[nc][dr] * lns[d0 + dr];
    gateT[(size_t)(d0 + dr) * SEQ + n0 + nc] = f2bf(v);
  }
}

// ---- kernel 3: tril-masked cast w fp32 -> bf16, lower-triangle tiles only -
// Grid = 528 blocks, one per 128x128 tile with j0 <= i0 (tiles strictly above
// the diagonal are never read by GEMM1, which stages rows [bm0,bm0+128) only
// for k < bm0+128). Halves read+write traffic vs the full-matrix cast.

__global__ __launch_bounds__(256) void cast_w_tril(const float* __restrict__ w,
                                                   unsigned short* __restrict__ wb) {
  int t = blockIdx.x;
  int i0 = (int)((sqrtf(8.f * (float)t + 1.f) - 1.f) * 0.5f);
  while ((i0 + 1) * (i0 + 2) / 2 <= t) i0++;
  while (i0 * (i0 + 1) / 2 > t) i0--;
  int j0 = t - i0 * (i0 + 1) / 2;  // j0 <= i0
  const bool interior = (j0 < i0);
  const int rowBase = i0 * 128, colBase = j0 * 128;
#pragma unroll
  for (int rnd = 0; rnd < 8; rnd++) {
    int idx = rnd * 256 + threadIdx.x;   // 0..2047
    int r = idx >> 4, g = idx & 15;      // row in tile, 8-elem group
    int m = rowBase + r, k = colBase + g * 8;
    size_t e = (size_t)m * SEQ + k;
    uint4 o;
    if (interior || k + 7 <= m) {  // fully inside lower triangle
      const float4* s = (const float4*)(w + e);
      float4 a = s[0], b = s[1];
      o.x = (unsigned)f2bf(a.x) | ((unsigned)f2bf(a.y) << 16);
      o.y = (unsigned)f2bf(a.z) | ((unsigned)f2bf(a.w) << 16);
      o.z = (unsigned)f2bf(b.x) | ((unsigned)f2bf(b.y) << 16);
      o.w = (unsigned)f2bf(b.z) | ((unsigned)f2bf(b.w) << 16);
    } else if (k > m) {  // fully above diagonal (within diagonal tile)
      o.x = o.y = o.z = o.w = 0u;
    } else {  // straddles the diagonal
      unsigned short tt[8];
#pragma unroll
      for (int j = 0; j < 8; j++) tt[j] = (k + j <= m) ? f2bf(w[e + j]) : (unsigned short)0;
      o.x = (unsigned)tt[0] | ((unsigned)tt[1] << 16);
      o.y = (unsigned)tt[2] | ((unsigned)tt[3] << 16);
      o.z = (unsigned)tt[4] | ((unsigned)tt[5] << 16);
      o.w = (unsigned)tt[6] | ((unsigned)tt[7] << 16);
    }
    *(uint4*)(wb + e) = o;
  }
}

// ---- kernel 4: transpose + cast proj_w -> projT[j][d] bf16 ----------------

__global__ __launch_bounds__(256) void proj_tr(const float* __restrict__ pw,
                                               unsigned short* __restrict__ pT) {
  __shared__ float tile[64][65];
  int j0 = blockIdx.x * 64;  // out-col tile (0..1023)
  int d0 = blockIdx.y * 64;  // d tile (0..2047)
#pragma unroll
  for (int i = 0; i < 16; i++) {
    int idx = threadIdx.x + i * 256;
    int r = idx >> 6, c = idx & 63;  // r = d offset, c = j offset
    tile[r][c] = pw[(size_t)(d0 + r) * DOUT + j0 + c];
  }
  __syncthreads();
#pragma unroll
  for (int i = 0; i < 16; i++) {
    int idx = threadIdx.x + i * 256;
    int jr = idx >> 6, dc = idx & 63;
    pT[(size_t)(j0 + jr) * DH + d0 + dc] = f2bf(tile[dc][jr]);
  }
}

// ---- MFMA GEMM, 128x64 tile, BK=64, STATIC double-buffer, 2 blocks/CU -----
// C = A(MxK) * BT(NxK)^T, bf16 in / fp32 acc. 4 waves 2x2; each wave owns a
// 64x32 subtile (4x2 16x16 acc tiles), 16 MFMA + 12 ds_read_b128 / wave-iter.
//
// Pipeline: stage(i+1)->buf1 issued BEFORE compute(i) on buf0; the
// __syncthreads() drain then waits on loads issued a full compute phase
// (~700 cyc) earlier, not freshly-issued ones (R5's single-buffer exposed the
// full L2/HBM latency every iter). Buffers are FOUR DISTINCT __shared__
// arrays with compile-time selection (loop unrolled x2) so LDS alias analysis
// can't force a conservative vmcnt(0) before the fragment reads (R4's dynamic
// buf[i&1] failure). Grid 512 = 2 blocks/CU co-resident covers the residue.
// LDS 48 KB/block -> 96 KB/CU.
//
// PAIR (GEMM1 causal): block (c,p) processes row-blocks {p, 31-p} as one
// flat pipeline of exactly 2+4*gridDim.y = 66 iters (uniform, no tail).
// total is always even; mid-epilogue index e1-1 is always odd -> fires after
// the buf1-compute of an unrolled pair. A is pre-masked tril.
// EPI==1: P[m][n] = bf16( xfull[m][n] * (acc + rbias[m]) )
// EPI==2: out[m][n] = acc + cbias[n]
//
// LDS: 128 B rows (BK=64) = exactly 32 banks; XOR-8 chunk swizzle (phys
// chunk = data chunk ^ (row&7)) -> 0 bank conflicts (verified R3/R5).

template <bool PAIR, int EPI>
__global__ __launch_bounds__(256) void gemm_db(const unsigned short* __restrict__ A,
                                               const unsigned short* __restrict__ BT,
                                               const float* __restrict__ xfull,
                                               const float* __restrict__ rbias,
                                               unsigned short* __restrict__ Pout,
                                               const float* __restrict__ cbias,
                                               float* __restrict__ out,
                                               int N, int K) {
  constexpr int BK = 64;
  __shared__ unsigned short sA0[128 * BK];  // 16 KB
  __shared__ unsigned short sA1[128 * BK];  // 16 KB
  __shared__ unsigned short sB0[64 * BK];   //  8 KB
  __shared__ unsigned short sB1[64 * BK];   //  8 KB

  const int tid = threadIdx.x;
  const int lane = tid & 63, wave = tid >> 6;
  const int quad = lane >> 4, l16 = lane & 15;
  const int wm = wave >> 1, wn = wave & 1;
  const int bn0 = blockIdx.x * 64;
  const int p = blockIdx.y;

  const int bm0a = p * 128;
  const int bm0b = PAIR ? (2 * (int)gridDim.y - 1 - p) * 128 : 0;
  const int e1 = PAIR ? 2 * (p + 1) : 0x7fffffff;
  const int total = PAIR ? (2 + 4 * (int)gridDim.y) : (K / BK);  // always even

  // staging slot s: row = s>>3, phys chunk = s&7, data chunk = (s&7)^(row&7)
  int sOff[4], sDst[4];
#pragma unroll
  for (int r = 0; r < 4; r++) {
    int idx = r * 256 + tid;
    int row = idx >> 3;
    sOff[r] = row * K + (((idx & 7) ^ (row & 7)) * 8);
    sDst[r] = idx * 8;
  }

  f32x4 acc[4][2] = {};

  auto stage = [&](int i, unsigned short* dA, unsigned short* dB) {
    int kk, bm;
    if (!PAIR || i < e1) { kk = i * BK; bm = bm0a; }
    else                 { kk = (i - e1) * BK; bm = bm0b; }
    const unsigned short* Ab = A + (size_t)bm * K + kk;
    const unsigned short* Bb = BT + (size_t)bn0 * K + kk;
#pragma unroll
    for (int r = 0; r < 4; r++) g2l16(Ab + sOff[r], dA + sDst[r]);
#pragma unroll
    for (int r = 0; r < 2; r++) g2l16(Bb + sOff[r], dB + sDst[r]);
  };

  auto compute = [&](const unsigned short* cA, const unsigned short* cB) {
    bf16x8 af[2][4], bf[2][2];
#pragma unroll
    for (int h = 0; h < 2; h++) {
#pragma unroll
      for (int i = 0; i < 4; i++) {
        int R = wm * 64 + i * 16 + l16;
        af[h][i] = *(const bf16x8*)&cA[R * BK + (((h * 4 + quad) ^ (R & 7)) * 8)];
      }
#pragma unroll
      for (int j = 0; j < 2; j++) {
        int R = wn * 32 + j * 16 + l16;
        bf[h][j] = *(const bf16x8*)&cB[R * BK + (((h * 4 + quad) ^ (R & 7)) * 8)];
      }
    }
#pragma unroll
    for (int h = 0; h < 2; h++)
#pragma unroll
      for (int i = 0; i < 4; i++)
#pragma unroll
        for (int j = 0; j < 2; j++)
          acc[i][j] = __builtin_amdgcn_mfma_f32_16x16x32_bf16(af[h][i], bf[h][j], acc[i][j], 0, 0, 0);
  };

  // epilogue — C/D layout: col = lane&15, row = quad*4 + reg (m89-verified)
  auto epilogue = [&](int bm0) {
#pragma unroll
    for (int i = 0; i < 4; i++) {
#pragma unroll
      for (int j = 0; j < 2; j++) {
        int col = bn0 + wn * 32 + j * 16 + l16;
#pragma unroll
        for (int r = 0; r < 4; r++) {
          int row = bm0 + wm * 64 + i * 16 + quad * 4 + r;
          float v = acc[i][j][r];
          if (EPI == 1) {
            float g = v + rbias[row];
            float pv = xfull[(size_t)row * (2 * DH) + col] * g;
            Pout[(size_t)row * N + col] = f2bf(pv);
          } else {
            out[(size_t)row * N + col] = v + cbias[col];
          }
        }
      }
    }
  };

  stage(0, sA0, sB0);
  __syncthreads();
  for (int i = 0; i < total; i += 2) {
    stage(i + 1, sA1, sB1);          // i+1 <= total-1: always valid
    compute(sA0, sB0);
    __syncthreads();                  // drains stage(i+1) (issued ~1 compute ago)
    if (i + 2 < total) stage(i + 2, sA0, sB0);
    compute(sA1, sB1);
    if (PAIR && (i + 1) == e1 - 1) {  // e1-1 is odd: lands here exactly
      epilogue(bm0a);
#pragma unroll
      for (int a = 0; a < 4; a++)
#pragma unroll
        for (int b = 0; b < 2; b++) acc[a][b] = (f32x4){0.f, 0.f, 0.f, 0.f};
    }
    __syncthreads();
  }
  epilogue(PAIR ? bm0b : bm0a);
}

// ---- launch ---------------------------------------------------------------

extern "C" void kernel_launch(void* const* d_in, const int* in_sizes, int n_in,
                              void* d_out, int out_size, void* d_ws, size_t ws_size,
                              hipStream_t stream) {
  (void)in_sizes; (void)n_in; (void)out_size; (void)ws_size;
  const float* x   = (const float*)d_in[0];
  const float* lns = (const float*)d_in[1];
  const float* w   = (const float*)d_in[2];
  const float* sb  = (const float*)d_in[3];
  const float* pw  = (const float*)d_in[4];
  const float* pb  = (const float*)d_in[5];
  float* out = (float*)d_out;

  char* p = (char*)d_ws;
  unsigned short* gateT = (unsigned short*)p; p += (size_t)DH * SEQ * 2;    // 16 MB
  unsigned short* wb    = (unsigned short*)p; p += (size_t)SEQ * SEQ * 2;   // 32 MB
  unsigned short* projT = (unsigned short*)p; p += (size_t)DOUT * DH * 2;   //  4 MB
  unsigned short* Pbuf  = (unsigned short*)p; p += (size_t)SEQ * DH * 2;    // 16 MB
  float* mv = (float*)p; p += (size_t)SEQ * 4;
  float* rv = (float*)p; p += (size_t)SEQ * 4;

  ln_stats<<<SEQ, 256, 0, stream>>>(x, mv, rv);
  norm_tr<<<dim3(DH / 64, SEQ / 64), 256, 0, stream>>>(x, mv, rv, lns, gateT);
  cast_w_tril<<<528, 256, 0, stream>>>(w, wb);  // 528 = lower-tri 128x128 tiles
  proj_tr<<<dim3(DOUT / 64, DH / 64), 256, 0, stream>>>(pw, projT);

  // GEMM1: gate2 = tril(w) @ gate  (M=4096, N=2048, K=4096)
  // 128x64 tiles, pairing {p, 31-p}: grid (32 cols, 16 pairs) = 512 uniform
  // 66-iter blocks = 2 blocks/CU, static double-buffer pipeline.
  gemm_db<true, 1><<<dim3(DH / 64, SEQ / 256), 256, 0, stream>>>(
      wb, gateT, x, sb, Pbuf, nullptr, nullptr, DH, SEQ);
  // GEMM2: out = P @ proj_w + proj_b  (M=4096, N=1024, K=2048)
  // grid (16 cols, 32 rows) = 512 uniform 32-iter blocks = 2 blocks/CU.
  gemm_db<false, 2><<<dim3(DOUT / 64, SEQ / 128), 256, 0, stream>>>(
      Pbuf, projT, nullptr, nullptr, nullptr, pb, out, DOUT, DH);
}